// Round 2
// baseline (25.340 us; speedup 1.0000x reference)
//
#include <hip/hip_runtime.h>

// ReservoirEmbedding: out[tok,:] = sum_r w_eff[reservoir_lookup[base_indices[tok], r], :]
// w_eff row 0 zeroed. base [16,2048] i32, lookup [50257,8] i32, weight [50257,128] f32.
//
// R1: gather loads issued via inline asm with `sc0` (L1 bypass) to test the
// L1-MSHR-saturation hypothesis; idx loads vectorized to 2x int4; 32-bit
// addressing; nontemporal output stores (output never re-read; keep the
// 25.7MB table resident in L2/L3).

#define VOCAB 50257
#define FEATURES 128
#define RESERVOIR 8
#define NTOK (16 * 2048)

typedef float float4v __attribute__((ext_vector_type(4)));

__global__ __launch_bounds__(256) void reservoir_embed_kernel(
    const int* __restrict__ base_indices,      // [NTOK]
    const int* __restrict__ reservoir_lookup,  // [VOCAB][RESERVOIR]
    const float* __restrict__ weight,          // [VOCAB][FEATURES]
    float* __restrict__ out)                   // [NTOK][FEATURES]
{
    const int gid  = blockIdx.x * blockDim.x + threadIdx.x;
    const int tok  = gid >> 5;        // 32 lanes per token
    const int lane = gid & 31;        // lane owns features [4*lane, 4*lane+4)

    const int base = base_indices[tok];
    // 8 indices as two int4 loads (32B-aligned: base*32 bytes).
    const int4* rlp = reinterpret_cast<const int4*>(reservoir_lookup + base * RESERVOIR);
    const int4 i0 = rlp[0];
    const int4 i1 = rlp[1];
    const int idx[RESERVOIR] = {i0.x, i0.y, i0.z, i0.w, i1.x, i1.y, i1.z, i1.w};

    // Issue all 8 gathered 16B loads with sc0 (bypass L1; L2/L3 behave normally).
    float4v rows[RESERVOIR];
#pragma unroll
    for (int r = 0; r < RESERVOIR; ++r) {
        const float* p = weight + (((unsigned)idx[r]) << 7) + (lane << 2);
        asm volatile("global_load_dwordx4 %0, %1, off sc0"
                     : "=v"(rows[r]) : "v"(p));
    }
    // Single drain; tying rows as "+v" gives the accumulate a dataflow dep on
    // this wait, so it cannot be scheduled before the loads complete.
    asm volatile("s_waitcnt vmcnt(0)"
                 : "+v"(rows[0]), "+v"(rows[1]), "+v"(rows[2]), "+v"(rows[3]),
                   "+v"(rows[4]), "+v"(rows[5]), "+v"(rows[6]), "+v"(rows[7]));

    float4v acc = {0.f, 0.f, 0.f, 0.f};
#pragma unroll
    for (int r = 0; r < RESERVOIR; ++r) {
        const float m = (idx[r] != 0) ? 1.0f : 0.0f;  // frozen row 0
        acc += m * rows[r];
    }

    float4v* op = reinterpret_cast<float4v*>(out + (unsigned)tok * FEATURES + (lane << 2));
    __builtin_nontemporal_store(acc, op);
}

extern "C" void kernel_launch(void* const* d_in, const int* in_sizes, int n_in,
                              void* d_out, int out_size, void* d_ws, size_t ws_size,
                              hipStream_t stream) {
    (void)in_sizes; (void)n_in; (void)out_size; (void)d_ws; (void)ws_size;
    const int*   base_indices     = (const int*)d_in[0];
    const int*   reservoir_lookup = (const int*)d_in[1];
    const float* weight           = (const float*)d_in[2];
    float*       out              = (float*)d_out;

    const int threads = 256;                 // 8 tokens per block
    const int total   = NTOK * 32;           // exact multiple of 256
    const int blocks  = total / threads;
    reservoir_embed_kernel<<<blocks, threads, 0, stream>>>(
        base_indices, reservoir_lookup, weight, out);
}

// Round 3
// 24.859 us; speedup vs baseline: 1.0193x; 1.0193x over previous
//
#include <hip/hip_runtime.h>

// ReservoirEmbedding: out[tok,:] = sum_r w_eff[reservoir_lookup[base_indices[tok], r], :]
// w_eff row 0 zeroed. base [16,2048] i32, lookup [50257,8] i32, weight [50257,128] f32.
//
// R2: 4 tokens per 32-lane group (4x per-wave memory-level parallelism; up to
// 32 gather instructions in flight per wave), single int4 base load, plain
// cached loads (sc0 was neutral in R1), nontemporal output stores.
// Grid = 1024 blocks -> ~16 waves/CU, all co-resident, no wave churn.

#define VOCAB 50257
#define FEATURES 128
#define RESERVOIR 8
#define NTOK (16 * 2048)
#define TPG 4   // tokens per 32-lane group

typedef float float4v __attribute__((ext_vector_type(4)));

__global__ __launch_bounds__(256) void reservoir_embed_kernel(
    const int* __restrict__ base_indices,      // [NTOK]
    const int* __restrict__ reservoir_lookup,  // [VOCAB][RESERVOIR]
    const float* __restrict__ weight,          // [VOCAB][FEATURES]
    float* __restrict__ out)                   // [NTOK][FEATURES]
{
    const int gid  = blockIdx.x * blockDim.x + threadIdx.x;
    const int grp  = gid >> 5;        // 32-lane group
    const int lane = gid & 31;        // lane owns features [4*lane, 4*lane+4)
    const int t0   = grp * TPG;       // first of 4 consecutive tokens

    // 4 base indices in one 16B load (t0 is 4-aligned).
    const int4 b4 = *reinterpret_cast<const int4*>(base_indices + t0);
    const int bases[TPG] = {b4.x, b4.y, b4.z, b4.w};

    // 8 reservoir indices per token, as 2x int4 each (rows are 32B-aligned).
    int idx[TPG][RESERVOIR];
#pragma unroll
    for (int t = 0; t < TPG; ++t) {
        const int4* rlp = reinterpret_cast<const int4*>(
            reservoir_lookup + bases[t] * RESERVOIR);
        const int4 i0 = rlp[0];
        const int4 i1 = rlp[1];
        idx[t][0] = i0.x; idx[t][1] = i0.y; idx[t][2] = i0.z; idx[t][3] = i0.w;
        idx[t][4] = i1.x; idx[t][5] = i1.y; idx[t][6] = i1.z; idx[t][7] = i1.w;
    }

    // 32 gathered float4 loads; compiler is free to issue them all before the
    // first accumulate (plenty of VGPR headroom at 256 threads/block).
    float4v acc[TPG];
#pragma unroll
    for (int t = 0; t < TPG; ++t) acc[t] = (float4v){0.f, 0.f, 0.f, 0.f};

#pragma unroll
    for (int t = 0; t < TPG; ++t) {
        float4v rows[RESERVOIR];
#pragma unroll
        for (int r = 0; r < RESERVOIR; ++r) {
            rows[r] = *reinterpret_cast<const float4v*>(
                weight + (((unsigned)idx[t][r]) << 7) + (lane << 2));
        }
#pragma unroll
        for (int r = 0; r < RESERVOIR; ++r) {
            const float m = (idx[t][r] != 0) ? 1.0f : 0.0f;  // frozen row 0
            acc[t] += m * rows[r];
        }
    }

#pragma unroll
    for (int t = 0; t < TPG; ++t) {
        float4v* op = reinterpret_cast<float4v*>(
            out + (unsigned)(t0 + t) * FEATURES + (lane << 2));
        __builtin_nontemporal_store(acc[t], op);
    }
}

extern "C" void kernel_launch(void* const* d_in, const int* in_sizes, int n_in,
                              void* d_out, int out_size, void* d_ws, size_t ws_size,
                              hipStream_t stream) {
    (void)in_sizes; (void)n_in; (void)out_size; (void)d_ws; (void)ws_size;
    const int*   base_indices     = (const int*)d_in[0];
    const int*   reservoir_lookup = (const int*)d_in[1];
    const float* weight           = (const float*)d_in[2];
    float*       out              = (float*)d_out;

    const int threads = 256;                       // 8 groups of 32 lanes
    const int groups  = NTOK / TPG;                // 8192 groups
    const int blocks  = groups * 32 / threads;     // 1024 blocks
    reservoir_embed_kernel<<<blocks, threads, 0, stream>>>(
        base_indices, reservoir_lookup, weight, out);
}